// Round 16
// baseline (261.517 us; speedup 1.0000x reference)
//
#include <hip/hip_runtime.h>
#include <hip/hip_fp16.h>

#define NN 100000
#define NE 1600000
#define NPB 128                        // nodes per bucket
#define NBUCK ((NN + NPB - 1) / NPB)   // 782
#define CAP 4096                       // reserved slots per bucket (align-16 slack incl)
#define PBLOCKS 128
#define PTPB 1024
#define EPB (NE / PBLOCKS)             // 12500
#define DUMMY 100000u                  // pad src: hws row NN is all-zero
#define SENT 0xFFFFFFFFu               // reservation-slack sentinel
#define GBLK 4096                      // gather blocks
#define NSLOT (GBLK * 8)               // 32768 half-wave slots (node per half-wave)

typedef unsigned int u32x4 __attribute__((ext_vector_type(4)));

// ---- bucket partition, 64B-aligned per-(block,bucket) runs: packed = (dst&127)<<17 | src ----
// Each block fills its own reservation slack with SENT (exclusive 64B lines).
__global__ __launch_bounds__(PTPB) void part_kernel(const int* __restrict__ src,
                                                    const int* __restrict__ dst,
                                                    unsigned int* __restrict__ bcount,
                                                    unsigned int* __restrict__ packed) {
    __shared__ unsigned int lcnt[NBUCK];
    __shared__ unsigned int lcur[NBUCK];
    __shared__ unsigned int lend[NBUCK];
    for (int i = threadIdx.x; i < NBUCK; i += PTPB) lcnt[i] = 0u;
    __syncthreads();
    int e0 = blockIdx.x * EPB;
    for (int e = e0 + threadIdx.x; e < e0 + EPB; e += PTPB)
        atomicAdd(&lcnt[((unsigned)dst[e]) >> 7], 1u);
    __syncthreads();
    for (int i = threadIdx.x; i < NBUCK; i += PTPB) {
        unsigned int c = lcnt[i];
        unsigned int rc = (c + 15u) & ~15u;              // 64B-aligned reservation
        unsigned int base = rc ? atomicAdd(&bcount[i], rc) : 0u;
        lcur[i] = base;
        lend[i] = base + rc;
    }
    __syncthreads();
    for (int e = e0 + threadIdx.x; e < e0 + EPB; e += PTPB) {
        unsigned int d = (unsigned)dst[e];
        unsigned int b = d >> 7;
        unsigned int pos = atomicAdd(&lcur[b], 1u);
        packed[(size_t)b * CAP + pos] = ((d & 127u) << 17) | (unsigned)src[e];
    }
    __syncthreads();
    for (int i = threadIdx.x; i < NBUCK; i += PTPB)      // fill own slack with SENT
        for (unsigned int j = lcur[i]; j < lend[i]; j++)
            packed[(size_t)i * CAP + j] = SENT;
}

// ---- per-bucket counting sort: permute writes DIRECTLY to global (in-place safe),
//      pad slots (to mult of 8) written as DUMMY. rsd = row_start | (pc/8)<<22 ----
__global__ __launch_bounds__(512) void sort_kernel(const unsigned int* __restrict__ bcount,
                                                   unsigned int* __restrict__ packed,
                                                   unsigned int* __restrict__ rsd,
                                                   float* __restrict__ dinv) {
    __shared__ unsigned int lraw[CAP];
    __shared__ unsigned int cnt[NPB];
    __shared__ unsigned int ps[NPB];   // inclusive prefix of PADDED counts
    __shared__ unsigned int cur[NPB];
    int b = blockIdx.x;
    int tid = threadIdx.x;
    if (tid < NPB) cnt[tid] = 0u;
    __syncthreads();
    unsigned int n = bcount[b];        // reserved total (includes SENT holes)
    unsigned int* pk = packed + (size_t)b * CAP;
    for (unsigned int i = tid; i < n; i += 512) {
        unsigned int p = pk[i];
        lraw[i] = p;
        if (p != SENT) atomicAdd(&cnt[p >> 17], 1u);
    }
    __syncthreads();                   // all of pk staged in LDS -> global writes safe
    if (tid < NPB) ps[tid] = (cnt[tid] + 7u) & ~7u;  // padded count
    __syncthreads();
    for (int off = 1; off < NPB; off <<= 1) {
        unsigned int t = (tid < NPB && tid >= off) ? ps[tid - off] : 0u;
        __syncthreads();
        if (tid < NPB) ps[tid] += t;
        __syncthreads();
    }
    if (tid < NPB) cur[tid] = ps[tid] - ((cnt[tid] + 7u) & ~7u);  // excl padded offset
    __syncthreads();
    for (unsigned int i = tid; i < n; i += 512) {
        unsigned int p = lraw[i];
        if (p != SENT) {
            unsigned int pos = atomicAdd(&cur[p >> 17], 1u);
            pk[pos] = p & 0x1FFFFu;    // direct global write, block-exclusive region
        }
    }
    if (tid < NPB) {
        int node = b * NPB + tid;
        if (node < NN) {
            unsigned int c = cnt[tid];
            unsigned int pc = (c + 7u) & ~7u;
            unsigned int lstart = ps[tid] - pc;
            for (unsigned int j = c; j < pc; j++) pk[lstart + j] = DUMMY;  // pad slots
            unsigned int rs = (unsigned int)(b * CAP) + lstart;  // < 2^22 (3.2M)
            rsd[node] = rs | ((pc >> 3) << 22);
            dinv[node] = rsqrtf((float)c + 1.0f);   // real deg + self-loop
        }
    }
}

// ---------------- embed MLP + hws1 = fp16((h @ Wg1) * dinv); zeros pad row NN ----------------
__global__ __launch_bounds__(256) void embed_kernel(
    const float* __restrict__ x, const float* __restrict__ We1, const float* __restrict__ be1,
    const float* __restrict__ We2, const float* __restrict__ be2, const float* __restrict__ Wg1,
    const float* __restrict__ dinv, __half* __restrict__ hws1, __half* __restrict__ hws2) {
    __shared__ float sWe1[6 * 64];
    __shared__ float sbe1[64];
    __shared__ float sWe2[64 * 32];
    __shared__ float sbe2[32];
    __shared__ float sWg1[32 * 32];
    for (int i = threadIdx.x; i < 6 * 64; i += 256) sWe1[i] = We1[i];
    for (int i = threadIdx.x; i < 64; i += 256) sbe1[i] = be1[i];
    for (int i = threadIdx.x; i < 64 * 32; i += 256) sWe2[i] = We2[i];
    for (int i = threadIdx.x; i < 32; i += 256) sbe2[i] = be2[i];
    for (int i = threadIdx.x; i < 32 * 32; i += 256) sWg1[i] = Wg1[i];
    __syncthreads();

    int node = blockIdx.x * 256 + threadIdx.x;
    if (node > NN) return;
    if (node == NN) {  // zero pad rows for DUMMY src
        for (int j = 0; j < 32; j++) {
            hws1[(size_t)NN * 32 + j] = __float2half(0.f);
            hws2[(size_t)NN * 32 + j] = __float2half(0.f);
        }
        return;
    }

    float xv[6];
#pragma unroll
    for (int k = 0; k < 6; k++) xv[k] = x[node * 6 + k];

    float h1[64];
#pragma unroll
    for (int j = 0; j < 64; j++) {
        float a = sbe1[j];
#pragma unroll
        for (int k = 0; k < 6; k++) a += xv[k] * sWe1[k * 64 + j];
        h1[j] = tanhf(a);
    }

    float h[32];
#pragma unroll 4
    for (int j = 0; j < 32; j++) {
        float a = sbe2[j];
#pragma unroll
        for (int k = 0; k < 64; k++) a += h1[k] * sWe2[k * 32 + j];
        h[j] = tanhf(a);
    }

    float di = dinv[node];
    __half* o = hws1 + (size_t)node * 32;
#pragma unroll 4
    for (int j = 0; j < 32; j++) {
        float a = 0.f;
#pragma unroll
        for (int k = 0; k < 32; k++) a += h[k] * sWg1[k * 32 + j];
        o[j] = __float2half(a * di);
    }
}

// ---- gather1: node per half-wave, W in VGPRs, NT index loads / NT output stores ----
__global__ __launch_bounds__(256) void gather1_kernel(
    const unsigned int* __restrict__ sorted, const unsigned int* __restrict__ rsd,
    const float* __restrict__ dinv, const __half* __restrict__ hws1,
    const float* __restrict__ bg1, const float* __restrict__ Wg2,
    __half* __restrict__ hws2) {
    int lane = threadIdx.x & 31;  // lane within half-wave
    int g = lane >> 4;            // edge group 0..1
    int p = lane & 15;            // feature pair
    int f = lane;                 // feature (epilogue)
    float wreg[32];
#pragma unroll
    for (int k = 0; k < 32; k++) wreg[k] = Wg2[k * 32 + f];  // column f in regs
    float bf = bg1[f];
    int slot = (blockIdx.x * 256 + threadIdx.x) >> 5;  // half-wave id
    const __half2* H = (const __half2*)hws1;
    for (int node = slot; node < NN; node += NSLOT) {
        unsigned int r = rsd[node];
        unsigned int base = r & 0x3FFFFFu;
        unsigned int d = (r >> 22) << 3;
        float ax = 0.f, ay = 0.f;
        for (unsigned int k = g * 4; k < d; k += 8) {  // 8 rows/node in flight
            u32x4 s4 = __builtin_nontemporal_load(
                reinterpret_cast<const u32x4*>(sorted + base + k));
            float2 v0 = __half22float2(H[(size_t)s4.x * 16 + p]);
            float2 v1 = __half22float2(H[(size_t)s4.y * 16 + p]);
            float2 v2 = __half22float2(H[(size_t)s4.z * 16 + p]);
            float2 v3 = __half22float2(H[(size_t)s4.w * 16 + p]);
            ax += (v0.x + v1.x) + (v2.x + v3.x);
            ay += (v0.y + v1.y) + (v2.y + v3.y);
        }
        ax += __shfl_xor(ax, 16); ay += __shfl_xor(ay, 16);  // combine 2 groups
        float2 sv = __half22float2(H[(size_t)node * 16 + p]);  // self-loop
        ax += sv.x; ay += sv.y;
        float ae = __shfl(ax, f >> 1, 32);
        float ao = __shfl(ay, f >> 1, 32);
        float av = (f & 1) ? ao : ae;
        float di = dinv[node];
        float h = di * av + bf;
        h = h > 0.f ? h : 0.f;
        float o = 0.f;
#pragma unroll
        for (int k = 0; k < 32; k++) o += __shfl(h, k, 32) * wreg[k];
        __builtin_nontemporal_store(__half_as_ushort(__float2half(o * di)),
                                    (unsigned short*)hws2 + (size_t)node * 32 + f);
    }
}

// ---- gather2: node per half-wave, conv2 + prediction MLP ----
__global__ __launch_bounds__(256) void gather2_kernel(
    const unsigned int* __restrict__ sorted, const unsigned int* __restrict__ rsd,
    const float* __restrict__ dinv, const __half* __restrict__ hws2,
    const float* __restrict__ bg2, const float* __restrict__ Wp1,
    const float* __restrict__ bp1, const float* __restrict__ Wp2,
    const float* __restrict__ bp2, float* __restrict__ out) {
    int lane = threadIdx.x & 31;
    int g = lane >> 4;
    int p = lane & 15;
    int f = lane;
    float wreg[32];
#pragma unroll
    for (int k = 0; k < 32; k++) wreg[k] = Wp1[k * 32 + f];
    float bgf = bg2[f];
    float b1f = bp1[f];
    float w2f = Wp2[f];
    float b2 = bp2[0];
    int slot = (blockIdx.x * 256 + threadIdx.x) >> 5;
    const __half2* H = (const __half2*)hws2;
    for (int node = slot; node < NN; node += NSLOT) {
        unsigned int r = rsd[node];
        unsigned int base = r & 0x3FFFFFu;
        unsigned int d = (r >> 22) << 3;
        float ax = 0.f, ay = 0.f;
        for (unsigned int k = g * 4; k < d; k += 8) {
            u32x4 s4 = __builtin_nontemporal_load(
                reinterpret_cast<const u32x4*>(sorted + base + k));
            float2 v0 = __half22float2(H[(size_t)s4.x * 16 + p]);
            float2 v1 = __half22float2(H[(size_t)s4.y * 16 + p]);
            float2 v2 = __half22float2(H[(size_t)s4.z * 16 + p]);
            float2 v3 = __half22float2(H[(size_t)s4.w * 16 + p]);
            ax += (v0.x + v1.x) + (v2.x + v3.x);
            ay += (v0.y + v1.y) + (v2.y + v3.y);
        }
        ax += __shfl_xor(ax, 16); ay += __shfl_xor(ay, 16);
        float2 sv = __half22float2(H[(size_t)node * 16 + p]);
        ax += sv.x; ay += sv.y;
        float ae = __shfl(ax, f >> 1, 32);
        float ao = __shfl(ay, f >> 1, 32);
        float av = (f & 1) ? ao : ae;
        float di = dinv[node];
        float h = di * av + bgf;
        h = h > 0.f ? h : 0.f;
        float pre = b1f;
#pragma unroll
        for (int k = 0; k < 32; k++) pre += __shfl(h, k, 32) * wreg[k];
        float t = tanhf(pre) * w2f;
#pragma unroll
        for (int off = 1; off < 32; off <<= 1) t += __shfl_xor(t, off);
        if (lane == 0) __builtin_nontemporal_store(tanhf(t + b2), out + node);
    }
}

extern "C" void kernel_launch(void* const* d_in, const int* in_sizes, int n_in,
                              void* d_out, int out_size, void* d_ws, size_t ws_size,
                              hipStream_t stream) {
    const float* x = (const float*)d_in[0];
    const int* edge = (const int*)d_in[1];  // [2, NE] int32
    const int* src = edge;
    const int* dst = edge + NE;
    const float* We1 = (const float*)d_in[2];
    const float* be1 = (const float*)d_in[3];
    const float* We2 = (const float*)d_in[4];
    const float* be2 = (const float*)d_in[5];
    const float* Wg1 = (const float*)d_in[6];
    const float* bg1 = (const float*)d_in[7];
    const float* Wg2 = (const float*)d_in[8];
    const float* bg2 = (const float*)d_in[9];
    const float* Wp1 = (const float*)d_in[10];
    const float* bp1 = (const float*)d_in[11];
    const float* Wp2 = (const float*)d_in[12];
    const float* bp2 = (const float*)d_in[13];
    float* out = (float*)d_out;

    // workspace (4B units):
    // bcount[1024] | dinv[NN] | rsd[NN] | packed[NBUCK*CAP] | hws1 | hws2
    unsigned int* bcount = (unsigned int*)d_ws;
    float* dinv = (float*)d_ws + 1024;
    unsigned int* rsd = (unsigned int*)d_ws + 1024 + NN;
    unsigned int* packed = (unsigned int*)d_ws + 1024 + 2 * NN;
    __half* hws1 = (__half*)((unsigned int*)d_ws + 1024 + 2 * NN + NBUCK * CAP);
    __half* hws2 = hws1 + (size_t)(NN + 1) * 32;

    (void)hipMemsetAsync(bcount, 0, 1024 * sizeof(unsigned int), stream);

    int gridN = (NN + 256) / 256;       // covers node NN (pad-row writer)

    part_kernel<<<PBLOCKS, PTPB, 0, stream>>>(src, dst, bcount, packed);
    sort_kernel<<<NBUCK, 512, 0, stream>>>(bcount, packed, rsd, dinv);
    embed_kernel<<<gridN, 256, 0, stream>>>(x, We1, be1, We2, be2, Wg1, dinv, hws1, hws2);
    gather1_kernel<<<GBLK, 256, 0, stream>>>(packed, rsd, dinv, hws1, bg1, Wg2, hws2);
    gather2_kernel<<<GBLK, 256, 0, stream>>>(packed, rsd, dinv, hws2, bg2, Wp1, bp1, Wp2, bp2, out);
}